// Round 5
// baseline (261.660 us; speedup 1.0000x reference)
//
#include <hip/hip_runtime.h>
#include <math.h>

#define BN_EPS 1e-5f

// ws layout (floats):
//   [0, N)        M      - folded message per node: sum over in-edges of (se*ea+te)
//   [N, N+16)     stats  - 0..4 xsum, 5..9 xsumsq, 10 esum, 11 esumsq
//   [N+16, N+64)  params - 0..24 A (folded 5x5), 25..29 c, 30..34 we1, 35 se, 36 te

__global__ void stats_kernel(const float* __restrict__ x, int N,
                             const float* __restrict__ ea, int E,
                             float* __restrict__ stats) {
    float s[5] = {0, 0, 0, 0, 0};
    float q[5] = {0, 0, 0, 0, 0};
    float es = 0, eq = 0;
    int tid = blockIdx.x * blockDim.x + threadIdx.x;
    int stride = gridDim.x * blockDim.x;

    // x: 5N floats, process 20-float chunks (4 nodes) with float4 loads.
    int nchunks = (int)((5LL * N) / 20);
    for (int c = tid; c < nchunks; c += stride) {
        const float4* p = (const float4*)(x + 20LL * c);
        float4 a0 = p[0], a1 = p[1], a2 = p[2], a3 = p[3], a4 = p[4];
        s[0] += a0.x + a1.y + a2.z + a3.w;
        q[0] += a0.x * a0.x + a1.y * a1.y + a2.z * a2.z + a3.w * a3.w;
        s[1] += a0.y + a1.z + a2.w + a4.x;
        q[1] += a0.y * a0.y + a1.z * a1.z + a2.w * a2.w + a4.x * a4.x;
        s[2] += a0.z + a1.w + a3.x + a4.y;
        q[2] += a0.z * a0.z + a1.w * a1.w + a3.x * a3.x + a4.y * a4.y;
        s[3] += a0.w + a2.x + a3.y + a4.z;
        q[3] += a0.w * a0.w + a2.x * a2.x + a3.y * a3.y + a4.z * a4.z;
        s[4] += a1.x + a2.y + a3.z + a4.w;
        q[4] += a1.x * a1.x + a2.y * a2.y + a3.z * a3.z + a4.w * a4.w;
    }
    for (int n = nchunks * 4 + tid; n < N; n += stride) {
#pragma unroll
        for (int j = 0; j < 5; ++j) {
            float v = x[n * 5 + j];
            s[j] += v;
            q[j] += v * v;
        }
    }
    int evec = E >> 2;
    for (int c = tid; c < evec; c += stride) {
        float4 v = ((const float4*)ea)[c];
        es += v.x + v.y + v.z + v.w;
        eq += v.x * v.x + v.y * v.y + v.z * v.z + v.w * v.w;
    }
    for (int e = (evec << 2) + tid; e < E; e += stride) {
        float v = ea[e];
        es += v;
        eq += v * v;
    }

    float vals[12] = {s[0], s[1], s[2], s[3], s[4], q[0], q[1], q[2], q[3], q[4], es, eq};
#pragma unroll
    for (int j = 0; j < 12; ++j) {
        for (int d = 32; d >= 1; d >>= 1) vals[j] += __shfl_down(vals[j], d);
    }
    __shared__ float bs[4][12];
    int lane = threadIdx.x & 63;
    int wid = threadIdx.x >> 6;
    if (lane == 0) {
#pragma unroll
        for (int j = 0; j < 12; ++j) bs[wid][j] = vals[j];
    }
    __syncthreads();
    if (threadIdx.x < 12) {
        float t = 0;
#pragma unroll
        for (int w = 0; w < 4; ++w) t += bs[w][threadIdx.x];
        atomicAdd(&stats[threadIdx.x], t);
    }
}

__global__ void finalize_kernel(const float* __restrict__ gx, const float* __restrict__ bx,
                                const float* __restrict__ ge, const float* __restrict__ be,
                                const float* __restrict__ Wg, const float* __restrict__ bg,
                                const float* __restrict__ We, const float* __restrict__ W1,
                                const float* __restrict__ b1,
                                const float* __restrict__ stats,
                                float* __restrict__ params, int N, int E) {
    __shared__ float Ms[25], sc[5], sh[5], bg1s[5], we1s[5];
    int t = threadIdx.x;
    if (t < 5) {
        float mu = stats[t] / (float)N;
        float var = stats[5 + t] / (float)N - mu * mu;
        float s = gx[t] * rsqrtf(var + BN_EPS);
        sc[t] = s;
        sh[t] = bx[t] - mu * s;
    }
    if (t < 25) {
        int j = t / 5, i = t % 5;
        float acc = 0;
        for (int k = 0; k < 110; ++k) acc += Wg[j * 110 + k] * W1[k * 5 + i];
        Ms[t] = acc;
    }
    if (t >= 25 && t < 30) {
        int i = t - 25;
        float acc = 0;
        for (int k = 0; k < 110; ++k) acc += We[k] * W1[k * 5 + i];
        we1s[i] = acc;
    }
    if (t >= 30 && t < 35) {
        int i = t - 30;
        float acc = 0;
        for (int k = 0; k < 110; ++k) acc += bg[k] * W1[k * 5 + i];
        bg1s[i] = acc;
    }
    __syncthreads();
    if (t < 25) params[t] = sc[t / 5] * Ms[t];
    if (t < 5) {
        float acc = bg1s[t] + b1[t];
#pragma unroll
        for (int j = 0; j < 5; ++j) acc += sh[j] * Ms[j * 5 + t];
        params[25 + t] = acc;
        params[30 + t] = we1s[t];
    }
    if (t == 35) {
        float mu = stats[10] / (float)E;
        float var = stats[11] / (float)E - mu * mu;
        float s = ge[0] * rsqrtf(var + BN_EPS);
        params[35] = s;               // se
        params[36] = be[0] - mu * s;  // te
    }
}

// 4 chunks (16 edges) per thread, all loads issued before any atomic:
// maximizes in-flight atomics per wave (Little's law) and amortizes drain.
__global__ void scatter_kernel(const float* __restrict__ ea, const int* __restrict__ dst,
                               int E, const float* __restrict__ params,
                               float* __restrict__ M) {
    float se = params[35];
    float te = params[36];
    int evec = E >> 2;
    int base = blockIdx.x * (blockDim.x * 4) + threadIdx.x;

    float4 v[4];
    int4 d[4];
    bool ok[4];
#pragma unroll
    for (int j = 0; j < 4; ++j) {
        int c = base + j * blockDim.x;
        ok[j] = (c < evec);
        if (ok[j]) {
            v[j] = ((const float4*)ea)[c];
            d[j] = ((const int4*)dst)[c];
        }
    }
#pragma unroll
    for (int j = 0; j < 4; ++j) {
        if (ok[j]) {
            atomicAdd(&M[d[j].x], se * v[j].x + te);
            atomicAdd(&M[d[j].y], se * v[j].y + te);
            atomicAdd(&M[d[j].z], se * v[j].z + te);
            atomicAdd(&M[d[j].w], se * v[j].w + te);
        }
    }
    // tail (E % 4)
    int gtid = blockIdx.x * blockDim.x + threadIdx.x;
    int gstride = gridDim.x * blockDim.x;
    for (int e = (evec << 2) + gtid; e < E; e += gstride) {
        atomicAdd(&M[dst[e]], se * ea[e] + te);
    }
}

__global__ void node_kernel(const float* __restrict__ x, const int* __restrict__ batch,
                            const float* __restrict__ M,
                            const float* __restrict__ params,
                            const float* __restrict__ W2, const float* __restrict__ b2,
                            float* __restrict__ out, int N) {
    __shared__ float P[37], W2s[25], b2s[5];
    __shared__ float xs[1280];
    int tid = threadIdx.x;
    if (tid < 37) P[tid] = params[tid];
    if (tid < 25) W2s[tid] = W2[tid];
    if (tid < 5) b2s[tid] = b2[tid];

    // stage this block's x slice (256 nodes * 5 feats) via coalesced float4
    long long base = (long long)blockIdx.x * 1280;
    int nfl = (int)(5LL * N - base);
    if (nfl > 1280) nfl = 1280;
    const float4* xp = (const float4*)(x + base);
    int nvec = nfl >> 2;
    for (int i = tid; i < nvec; i += 256) ((float4*)xs)[i] = xp[i];
    for (int i = (nvec << 2) + tid; i < nfl; i += 256) xs[i] = x[base + i];
    __syncthreads();

    int n = blockIdx.x * blockDim.x + tid;
    int lane = tid & 63;
    int b = -1;
    float o[5] = {0, 0, 0, 0, 0};
    if (n < N) {
        b = batch[n];
        float msg = M[n];
        float r[5];
#pragma unroll
        for (int i = 0; i < 5; ++i) r[i] = P[25 + i] + msg * P[30 + i];
#pragma unroll
        for (int j = 0; j < 5; ++j) {
            float xv = xs[tid * 5 + j];
#pragma unroll
            for (int i = 0; i < 5; ++i) r[i] += xv * P[j * 5 + i];
        }
#pragma unroll
        for (int i = 0; i < 5; ++i) {
            float v = r[i];
            r[i] = v / (1.0f + __expf(-v));  // swish
        }
#pragma unroll
        for (int i = 0; i < 5; ++i) {
            float acc = b2s[i];
#pragma unroll
            for (int k = 0; k < 5; ++k) acc += r[k] * W2s[k * 5 + i];
            o[i] = acc;
        }
    }

    // wave-level segmented reduction (batch sorted -> contiguous segments)
#pragma unroll
    for (int d = 1; d < 64; d <<= 1) {
        int nb = __shfl_down(b, d);
        float t0 = __shfl_down(o[0], d);
        float t1 = __shfl_down(o[1], d);
        float t2 = __shfl_down(o[2], d);
        float t3 = __shfl_down(o[3], d);
        float t4 = __shfl_down(o[4], d);
        if (lane + d < 64 && nb == b) {
            o[0] += t0; o[1] += t1; o[2] += t2; o[3] += t3; o[4] += t4;
        }
    }
    int pb = __shfl_up(b, 1);
    bool head = (lane == 0) || (pb != b);
    if (head && b >= 0) {
#pragma unroll
        for (int i = 0; i < 5; ++i) atomicAdd(&out[b * 5 + i], o[i]);
    }
}

extern "C" void kernel_launch(void* const* d_in, const int* in_sizes, int n_in,
                              void* d_out, int out_size, void* d_ws, size_t ws_size,
                              hipStream_t stream) {
    const float* x = (const float*)d_in[0];
    const float* ea = (const float*)d_in[1];
    const int* batch = (const int*)d_in[2];
    const int* ei = (const int*)d_in[3];
    const float* gx = (const float*)d_in[4];
    const float* bx = (const float*)d_in[5];
    const float* ge = (const float*)d_in[6];
    const float* be = (const float*)d_in[7];
    const float* Wg = (const float*)d_in[8];
    const float* bg = (const float*)d_in[9];
    const float* We = (const float*)d_in[10];
    const float* W1 = (const float*)d_in[11];
    const float* b1 = (const float*)d_in[12];
    const float* W2 = (const float*)d_in[13];
    const float* b2 = (const float*)d_in[14];

    int N = in_sizes[2];  // n_nodes
    int E = in_sizes[1];  // n_edges

    float* ws = (float*)d_ws;
    float* M = ws;
    float* stats = ws + N;
    float* params = stats + 16;
    float* out = (float*)d_out;

    hipMemsetAsync(d_ws, 0, ((size_t)N + 64) * sizeof(float), stream);
    hipMemsetAsync(d_out, 0, (size_t)out_size * sizeof(float), stream);

    stats_kernel<<<2048, 256, 0, stream>>>(x, N, ea, E, stats);
    finalize_kernel<<<1, 64, 0, stream>>>(gx, bx, ge, be, Wg, bg, We, W1, b1,
                                          stats, params, N, E);

    int evec = E >> 2;
    int sblocks = (evec + 1023) / 1024;
    if (sblocks < 1) sblocks = 1;
    scatter_kernel<<<sblocks, 256, 0, stream>>>(ea, ei + E, E, params, M);

    node_kernel<<<(N + 255) / 256, 256, 0, stream>>>(x, batch, M, params, W2, b2, out, N);
}

// Round 16
// 246.249 us; speedup vs baseline: 1.0626x; 1.0626x over previous
//
#include <hip/hip_runtime.h>
#include <math.h>

#define BN_EPS 1e-5f
#define FXSCALE 1048576.0f      // 2^20 fixed-point scale for message accumulation
#define FXINV   (1.0f / 1048576.0f)

// ws layout (4-byte words), R = replicas (8 if ws fits, else 1):
//   [0, R*N)        Mrep   - int32 fixed-point message accumulators, replica r at [r*N, (r+1)*N)
//   [R*N, R*N+16)   stats  - f32: 0..4 xsum, 5..9 xsumsq, 10 esum, 11 esumsq
//   [R*N+16, +48)   params - f32: 0..24 A (folded 5x5), 25..29 c, 30..34 we1, 35 se, 36 te

__global__ void stats_kernel(const float* __restrict__ x, int N,
                             const float* __restrict__ ea, int E,
                             float* __restrict__ stats) {
    float s[5] = {0, 0, 0, 0, 0};
    float q[5] = {0, 0, 0, 0, 0};
    float es = 0, eq = 0;
    int tid = blockIdx.x * blockDim.x + threadIdx.x;
    int stride = gridDim.x * blockDim.x;

    // x: 5N floats, process 20-float chunks (4 nodes) with float4 loads.
    int nchunks = (int)((5LL * N) / 20);
    for (int c = tid; c < nchunks; c += stride) {
        const float4* p = (const float4*)(x + 20LL * c);
        float4 a0 = p[0], a1 = p[1], a2 = p[2], a3 = p[3], a4 = p[4];
        s[0] += a0.x + a1.y + a2.z + a3.w;
        q[0] += a0.x * a0.x + a1.y * a1.y + a2.z * a2.z + a3.w * a3.w;
        s[1] += a0.y + a1.z + a2.w + a4.x;
        q[1] += a0.y * a0.y + a1.z * a1.z + a2.w * a2.w + a4.x * a4.x;
        s[2] += a0.z + a1.w + a3.x + a4.y;
        q[2] += a0.z * a0.z + a1.w * a1.w + a3.x * a3.x + a4.y * a4.y;
        s[3] += a0.w + a2.x + a3.y + a4.z;
        q[3] += a0.w * a0.w + a2.x * a2.x + a3.y * a3.y + a4.z * a4.z;
        s[4] += a1.x + a2.y + a3.z + a4.w;
        q[4] += a1.x * a1.x + a2.y * a2.y + a3.z * a3.z + a4.w * a4.w;
    }
    for (int n = nchunks * 4 + tid; n < N; n += stride) {
#pragma unroll
        for (int j = 0; j < 5; ++j) {
            float v = x[n * 5 + j];
            s[j] += v;
            q[j] += v * v;
        }
    }
    int evec = E >> 2;
    for (int c = tid; c < evec; c += stride) {
        float4 v = ((const float4*)ea)[c];
        es += v.x + v.y + v.z + v.w;
        eq += v.x * v.x + v.y * v.y + v.z * v.z + v.w * v.w;
    }
    for (int e = (evec << 2) + tid; e < E; e += stride) {
        float v = ea[e];
        es += v;
        eq += v * v;
    }

    float vals[12] = {s[0], s[1], s[2], s[3], s[4], q[0], q[1], q[2], q[3], q[4], es, eq};
#pragma unroll
    for (int j = 0; j < 12; ++j) {
        for (int d = 32; d >= 1; d >>= 1) vals[j] += __shfl_down(vals[j], d);
    }
    __shared__ float bs[4][12];
    int lane = threadIdx.x & 63;
    int wid = threadIdx.x >> 6;
    if (lane == 0) {
#pragma unroll
        for (int j = 0; j < 12; ++j) bs[wid][j] = vals[j];
    }
    __syncthreads();
    if (threadIdx.x < 12) {
        float t = 0;
#pragma unroll
        for (int w = 0; w < 4; ++w) t += bs[w][threadIdx.x];
        atomicAdd(&stats[threadIdx.x], t);
    }
}

__global__ void finalize_kernel(const float* __restrict__ gx, const float* __restrict__ bx,
                                const float* __restrict__ ge, const float* __restrict__ be,
                                const float* __restrict__ Wg, const float* __restrict__ bg,
                                const float* __restrict__ We, const float* __restrict__ W1,
                                const float* __restrict__ b1,
                                const float* __restrict__ stats,
                                float* __restrict__ params, int N, int E) {
    __shared__ float Ms[25], sc[5], sh[5], bg1s[5], we1s[5];
    int t = threadIdx.x;
    if (t < 5) {
        float mu = stats[t] / (float)N;
        float var = stats[5 + t] / (float)N - mu * mu;
        float s = gx[t] * rsqrtf(var + BN_EPS);
        sc[t] = s;
        sh[t] = bx[t] - mu * s;
    }
    if (t < 25) {
        int j = t / 5, i = t % 5;
        float acc = 0;
        for (int k = 0; k < 110; ++k) acc += Wg[j * 110 + k] * W1[k * 5 + i];
        Ms[t] = acc;
    }
    if (t >= 25 && t < 30) {
        int i = t - 25;
        float acc = 0;
        for (int k = 0; k < 110; ++k) acc += We[k] * W1[k * 5 + i];
        we1s[i] = acc;
    }
    if (t >= 30 && t < 35) {
        int i = t - 30;
        float acc = 0;
        for (int k = 0; k < 110; ++k) acc += bg[k] * W1[k * 5 + i];
        bg1s[i] = acc;
    }
    __syncthreads();
    if (t < 25) params[t] = sc[t / 5] * Ms[t];
    if (t < 5) {
        float acc = bg1s[t] + b1[t];
#pragma unroll
        for (int j = 0; j < 5; ++j) acc += sh[j] * Ms[j * 5 + t];
        params[25 + t] = acc;
        params[30 + t] = we1s[t];
    }
    if (t == 35) {
        float mu = stats[10] / (float)E;
        float var = stats[11] / (float)E - mu * mu;
        float s = ge[0] * rsqrtf(var + BN_EPS);
        params[35] = s;               // se
        params[36] = be[0] - mu * s;  // te
    }
}

// Scatter with XCD-replicated accumulators:
// R==8: int32 fixed-point atomics at WORKGROUP scope -> execute cached in the
//       XCD-local TCC (no cross-XCD coherence needed: replica r is only ever
//       touched by blocks whose HW_REG_XCC_ID == r). End-of-kernel agent
//       release writes back dirty L2 (same mechanism that makes all our
//       cross-kernel plain stores visible).
// R==1: fallback, agent-scope (memory-side) atomics — correct, old speed.
__global__ void scatter_kernel(const float* __restrict__ ea, const int* __restrict__ dst,
                               int E, const float* __restrict__ params,
                               int* __restrict__ Mrep, int N, int R) {
    float se = params[35];
    float te = params[36];
    int rep = 0;
    if (R == 8) {
        unsigned xcc;
        asm volatile("s_getreg_b32 %0, hwreg(HW_REG_XCC_ID)" : "=s"(xcc));
        rep = (int)(xcc & 7u);
    }
    int* __restrict__ M = Mrep + (size_t)rep * N;

    int evec = E >> 2;
    int base = blockIdx.x * (blockDim.x * 4) + threadIdx.x;

    float4 v[4];
    int4 d[4];
    bool ok[4];
#pragma unroll
    for (int j = 0; j < 4; ++j) {
        int c = base + j * blockDim.x;
        ok[j] = (c < evec);
        if (ok[j]) {
            v[j] = ((const float4*)ea)[c];
            d[j] = ((const int4*)dst)[c];
        }
    }
    if (R == 8) {
#pragma unroll
        for (int j = 0; j < 4; ++j) {
            if (ok[j]) {
                __hip_atomic_fetch_add(&M[d[j].x], __float2int_rn((se * v[j].x + te) * FXSCALE),
                                       __ATOMIC_RELAXED, __HIP_MEMORY_SCOPE_WORKGROUP);
                __hip_atomic_fetch_add(&M[d[j].y], __float2int_rn((se * v[j].y + te) * FXSCALE),
                                       __ATOMIC_RELAXED, __HIP_MEMORY_SCOPE_WORKGROUP);
                __hip_atomic_fetch_add(&M[d[j].z], __float2int_rn((se * v[j].z + te) * FXSCALE),
                                       __ATOMIC_RELAXED, __HIP_MEMORY_SCOPE_WORKGROUP);
                __hip_atomic_fetch_add(&M[d[j].w], __float2int_rn((se * v[j].w + te) * FXSCALE),
                                       __ATOMIC_RELAXED, __HIP_MEMORY_SCOPE_WORKGROUP);
            }
        }
    } else {
#pragma unroll
        for (int j = 0; j < 4; ++j) {
            if (ok[j]) {
                __hip_atomic_fetch_add(&M[d[j].x], __float2int_rn((se * v[j].x + te) * FXSCALE),
                                       __ATOMIC_RELAXED, __HIP_MEMORY_SCOPE_AGENT);
                __hip_atomic_fetch_add(&M[d[j].y], __float2int_rn((se * v[j].y + te) * FXSCALE),
                                       __ATOMIC_RELAXED, __HIP_MEMORY_SCOPE_AGENT);
                __hip_atomic_fetch_add(&M[d[j].z], __float2int_rn((se * v[j].z + te) * FXSCALE),
                                       __ATOMIC_RELAXED, __HIP_MEMORY_SCOPE_AGENT);
                __hip_atomic_fetch_add(&M[d[j].w], __float2int_rn((se * v[j].w + te) * FXSCALE),
                                       __ATOMIC_RELAXED, __HIP_MEMORY_SCOPE_AGENT);
            }
        }
    }
    // tail (E % 4)
    int gtid = blockIdx.x * blockDim.x + threadIdx.x;
    int gstride = gridDim.x * blockDim.x;
    for (int e = (evec << 2) + gtid; e < E; e += gstride) {
        int val = __float2int_rn((se * ea[e] + te) * FXSCALE);
        if (R == 8)
            __hip_atomic_fetch_add(&M[dst[e]], val, __ATOMIC_RELAXED, __HIP_MEMORY_SCOPE_WORKGROUP);
        else
            __hip_atomic_fetch_add(&M[dst[e]], val, __ATOMIC_RELAXED, __HIP_MEMORY_SCOPE_AGENT);
    }
}

__global__ void node_kernel(const float* __restrict__ x, const int* __restrict__ batch,
                            const int* __restrict__ Mrep, int R,
                            const float* __restrict__ params,
                            const float* __restrict__ W2, const float* __restrict__ b2,
                            float* __restrict__ out, int N) {
    __shared__ float P[37], W2s[25], b2s[5];
    __shared__ float xs[1280];
    int tid = threadIdx.x;
    if (tid < 37) P[tid] = params[tid];
    if (tid < 25) W2s[tid] = W2[tid];
    if (tid < 5) b2s[tid] = b2[tid];

    // stage this block's x slice (256 nodes * 5 feats) via coalesced float4
    long long base = (long long)blockIdx.x * 1280;
    int nfl = (int)(5LL * N - base);
    if (nfl > 1280) nfl = 1280;
    const float4* xp = (const float4*)(x + base);
    int nvec = nfl >> 2;
    for (int i = tid; i < nvec; i += 256) ((float4*)xs)[i] = xp[i];
    for (int i = (nvec << 2) + tid; i < nfl; i += 256) xs[i] = x[base + i];
    __syncthreads();

    int n = blockIdx.x * blockDim.x + tid;
    int lane = tid & 63;
    int b = -1;
    float o[5] = {0, 0, 0, 0, 0};
    if (n < N) {
        b = batch[n];
        int acc = Mrep[n];
        if (R == 8) {
#pragma unroll
            for (int r = 1; r < 8; ++r) acc += Mrep[(size_t)r * N + n];
        }
        float msg = (float)acc * FXINV;
        float r[5];
#pragma unroll
        for (int i = 0; i < 5; ++i) r[i] = P[25 + i] + msg * P[30 + i];
#pragma unroll
        for (int j = 0; j < 5; ++j) {
            float xv = xs[tid * 5 + j];
#pragma unroll
            for (int i = 0; i < 5; ++i) r[i] += xv * P[j * 5 + i];
        }
#pragma unroll
        for (int i = 0; i < 5; ++i) {
            float v = r[i];
            r[i] = v / (1.0f + __expf(-v));  // swish
        }
#pragma unroll
        for (int i = 0; i < 5; ++i) {
            float acc2 = b2s[i];
#pragma unroll
            for (int k = 0; k < 5; ++k) acc2 += r[k] * W2s[k * 5 + i];
            o[i] = acc2;
        }
    }

    // wave-level segmented reduction (batch sorted -> contiguous segments)
#pragma unroll
    for (int d = 1; d < 64; d <<= 1) {
        int nb = __shfl_down(b, d);
        float t0 = __shfl_down(o[0], d);
        float t1 = __shfl_down(o[1], d);
        float t2 = __shfl_down(o[2], d);
        float t3 = __shfl_down(o[3], d);
        float t4 = __shfl_down(o[4], d);
        if (lane + d < 64 && nb == b) {
            o[0] += t0; o[1] += t1; o[2] += t2; o[3] += t3; o[4] += t4;
        }
    }
    int pb = __shfl_up(b, 1);
    bool head = (lane == 0) || (pb != b);
    if (head && b >= 0) {
#pragma unroll
        for (int i = 0; i < 5; ++i) atomicAdd(&out[b * 5 + i], o[i]);
    }
}

extern "C" void kernel_launch(void* const* d_in, const int* in_sizes, int n_in,
                              void* d_out, int out_size, void* d_ws, size_t ws_size,
                              hipStream_t stream) {
    const float* x = (const float*)d_in[0];
    const float* ea = (const float*)d_in[1];
    const int* batch = (const int*)d_in[2];
    const int* ei = (const int*)d_in[3];
    const float* gx = (const float*)d_in[4];
    const float* bx = (const float*)d_in[5];
    const float* ge = (const float*)d_in[6];
    const float* be = (const float*)d_in[7];
    const float* Wg = (const float*)d_in[8];
    const float* bg = (const float*)d_in[9];
    const float* We = (const float*)d_in[10];
    const float* W1 = (const float*)d_in[11];
    const float* b1 = (const float*)d_in[12];
    const float* W2 = (const float*)d_in[13];
    const float* b2 = (const float*)d_in[14];

    int N = in_sizes[2];  // n_nodes
    int E = in_sizes[1];  // n_edges

    // choose replica count by workspace size
    size_t needRep = ((size_t)8 * N + 64) * 4;
    int R = (ws_size >= needRep) ? 8 : 1;

    int* Mrep = (int*)d_ws;
    float* stats = (float*)d_ws + (size_t)R * N;
    float* params = stats + 16;
    float* out = (float*)d_out;

    hipMemsetAsync(d_ws, 0, ((size_t)R * N + 64) * sizeof(int), stream);
    hipMemsetAsync(d_out, 0, (size_t)out_size * sizeof(float), stream);

    stats_kernel<<<2048, 256, 0, stream>>>(x, N, ea, E, stats);
    finalize_kernel<<<1, 64, 0, stream>>>(gx, bx, ge, be, Wg, bg, We, W1, b1,
                                          stats, params, N, E);

    int evec = E >> 2;
    int sblocks = (evec + 1023) / 1024;
    if (sblocks < 1) sblocks = 1;
    scatter_kernel<<<sblocks, 256, 0, stream>>>(ea, ei + E, E, params, Mrep, N, R);

    node_kernel<<<(N + 255) / 256, 256, 0, stream>>>(x, batch, Mrep, R, params, W2, b2, out, N);
}